// Round 1
// baseline (1973.385 us; speedup 1.0000x reference)
//
#include <hip/hip_runtime.h>
#include <hip/hip_bf16.h>
#include <stdint.h>

#define T_LEN   2048
#define BATCH   4
#define DMODEL  1024
#define DINNER  2048
#define DSTATE  16
#define DTRANK  64
#define MROWS   (BATCH*T_LEN)   // 8192

typedef __bf16 bf16x8_t __attribute__((ext_vector_type(8)));
typedef float  f32x4_t  __attribute__((ext_vector_type(4)));

__device__ __forceinline__ uint16_t f2b(float f) {
    uint32_t u = __float_as_uint(f);
    u += 0x7fffu + ((u >> 16) & 1u);          // round-to-nearest-even
    return (uint16_t)(u >> 16);
}
__device__ __forceinline__ float b2f(uint16_t h) {
    return __uint_as_float(((uint32_t)h) << 16);
}

// ---------------------------------------------------------------------------
// x (t,b,c) fp32  ->  xb16 (b*T+t, c) bf16   (permute + convert)
// grid: 8192 blocks (one per (t,b) row), 256 threads, 4 elems/thread
// ---------------------------------------------------------------------------
__global__ __launch_bounds__(256) void convert_x_kernel(
    const float* __restrict__ x, uint16_t* __restrict__ xb)
{
    int tb = blockIdx.x;            // 0..8191, = t*4 + b
    int t = tb >> 2, b = tb & 3;
    int c = threadIdx.x * 4;
    const float4 v = *(const float4*)(x + ((size_t)tb) * DMODEL + c);
    uint16_t* dst = xb + ((size_t)(b * T_LEN + t)) * DMODEL + c;
    uint2 p;
    p.x = (uint32_t)f2b(v.x) | ((uint32_t)f2b(v.y) << 16);
    p.y = (uint32_t)f2b(v.z) | ((uint32_t)f2b(v.w) << 16);
    *(uint2*)dst = p;
}

// ---------------------------------------------------------------------------
// transpose + convert: src fp32 [R][C] -> dst bf16 [Cpad][R], zero-fill c>=C
// block (32,8); grid (ceil(R/32), ceil(Cpad/32))
// ---------------------------------------------------------------------------
__global__ __launch_bounds__(256) void transpose_cvt_kernel(
    const float* __restrict__ src, uint16_t* __restrict__ dst,
    int R, int C, int Cpad)
{
    __shared__ float tile[32][33];
    int r0 = blockIdx.x * 32;
    int c0 = blockIdx.y * 32;
    int tx = threadIdx.x, ty = threadIdx.y;
#pragma unroll
    for (int i = 0; i < 32; i += 8) {
        int r = r0 + ty + i, c = c0 + tx;
        tile[ty + i][tx] = (r < R && c < C) ? src[(size_t)r * C + c] : 0.f;
    }
    __syncthreads();
#pragma unroll
    for (int i = 0; i < 32; i += 8) {
        int dr = c0 + ty + i;   // dst row = src col
        int dc = r0 + tx;       // dst col = src row
        if (dr < Cpad && dc < R) dst[(size_t)dr * R + dc] = f2b(tile[tx][ty + i]);
    }
}

// ---------------------------------------------------------------------------
// Generic bf16 MFMA GEMM: C[M][N] = A[M][K] * Bt[N][K]^T
//   BM=BN=128, BK=32, 256 threads (4 waves, each 64x64 = 4x4 MFMA 16x16x32)
//   M multiple of 128; Bt must have ceil(N/128)*128 rows allocated; K % 32 == 0
// Epilogues:
//   0: store bf16 row-major (ldc)
//   1: store fp32 row-major with col<N guard (ldc)
//   2: softplus(acc + bias[col]) -> bf16 (ldc)
//   3: fp32 store remapped: row=b*T+t -> out[(t*BATCH+b)*ldc + col]
// ---------------------------------------------------------------------------
#define EPI_BF16  0
#define EPI_F32G  1
#define EPI_SP    2
#define EPI_REMAP 3

template <int EPI>
__global__ __launch_bounds__(256) void gemm_bt_kernel(
    const uint16_t* __restrict__ A, const uint16_t* __restrict__ Bt,
    void* __restrict__ Cout, const float* __restrict__ bias,
    int N, int K, int ldc)
{
    __shared__ uint16_t As[128 * 32];
    __shared__ uint16_t Bs[128 * 32];

    int tid = threadIdx.x;
    int bm = blockIdx.x * 128, bn = blockIdx.y * 128;

    // staging pointers: chunk tid -> row tid>>2, col (tid&3)*8 ; +256 -> row+64
    const uint16_t* ap0 = A  + (size_t)(bm + (tid >> 2)) * K + (tid & 3) * 8;
    const uint16_t* ap1 = ap0 + (size_t)64 * K;
    const uint16_t* bp0 = Bt + (size_t)(bn + (tid >> 2)) * K + (tid & 3) * 8;
    const uint16_t* bp1 = bp0 + (size_t)64 * K;

    f32x4_t acc[4][4];
#pragma unroll
    for (int i = 0; i < 4; i++)
#pragma unroll
        for (int j = 0; j < 4; j++) acc[i][j] = (f32x4_t){0.f, 0.f, 0.f, 0.f};

    int wid = tid >> 6, lane = tid & 63;
    int wm = (wid & 1) * 64, wn = (wid >> 1) * 64;
    int lr = lane & 15, lq = lane >> 4;
    const uint16_t* Afrag = &As[(wm + lr) * 32 + lq * 8];
    const uint16_t* Bfrag = &Bs[(wn + lr) * 32 + lq * 8];

    for (int k0 = 0; k0 < K; k0 += 32) {
        uint4 a0 = *(const uint4*)ap0; uint4 a1 = *(const uint4*)ap1;
        uint4 b0 = *(const uint4*)bp0; uint4 b1 = *(const uint4*)bp1;
        ap0 += 32; ap1 += 32; bp0 += 32; bp1 += 32;
        __syncthreads();
        *(uint4*)&As[(size_t)tid * 8]         = a0;
        *(uint4*)&As[(size_t)(tid + 256) * 8] = a1;
        *(uint4*)&Bs[(size_t)tid * 8]         = b0;
        *(uint4*)&Bs[(size_t)(tid + 256) * 8] = b1;
        __syncthreads();

        bf16x8_t av[4], bv[4];
#pragma unroll
        for (int i = 0; i < 4; i++) av[i] = *(const bf16x8_t*)(Afrag + i * 512);
#pragma unroll
        for (int j = 0; j < 4; j++) bv[j] = *(const bf16x8_t*)(Bfrag + j * 512);
#pragma unroll
        for (int i = 0; i < 4; i++)
#pragma unroll
            for (int j = 0; j < 4; j++)
                acc[i][j] = __builtin_amdgcn_mfma_f32_16x16x32_bf16(
                    av[i], bv[j], acc[i][j], 0, 0, 0);
    }

#pragma unroll
    for (int i = 0; i < 4; i++) {
#pragma unroll
        for (int j = 0; j < 4; j++) {
            int col = bn + wn + j * 16 + lr;
#pragma unroll
            for (int r = 0; r < 4; r++) {
                int row = bm + wm + i * 16 + lq * 4 + r;
                float v = acc[i][j][r];
                if (EPI == EPI_BF16) {
                    ((uint16_t*)Cout)[(size_t)row * ldc + col] = f2b(v);
                } else if (EPI == EPI_F32G) {
                    if (col < N) ((float*)Cout)[(size_t)row * ldc + col] = v;
                } else if (EPI == EPI_SP) {
                    float xv = v + bias[col];
                    float sp = (xv > 15.f) ? xv : __logf(1.f + __expf(xv));
                    ((uint16_t*)Cout)[(size_t)row * ldc + col] = f2b(sp);
                } else {
                    int bb = row >> 11, tt = row & (T_LEN - 1);
                    ((float*)Cout)[((size_t)(tt * BATCH + bb)) * ldc + col] = v;
                }
            }
        }
    }
}

// ---------------------------------------------------------------------------
// depthwise causal conv (width 4) + bias + SiLU:
//   u16[m][d] = silu( sum_j z16[m-3+j][d] * cw[d][j] + cb[d] ), t-window guard
// z16 rows are 4096 wide (u_raw = cols 0..2047). 2 cols/thread.
// ---------------------------------------------------------------------------
__global__ __launch_bounds__(256) void conv_silu_kernel(
    const uint16_t* __restrict__ z, const float* __restrict__ cw,
    const float* __restrict__ cb, uint16_t* __restrict__ u)
{
    int idx = blockIdx.x * 256 + threadIdx.x;   // 0 .. 8192*1024-1
    int m  = idx >> 10;
    int dp = (idx & 1023) << 1;
    int t  = m & (T_LEN - 1);
    float a0 = cb[dp], a1 = cb[dp + 1];
#pragma unroll
    for (int j = 0; j < 4; j++) {
        int tt = t - 3 + j;
        if (tt >= 0) {
            uint32_t v = *(const uint32_t*)(z + (size_t)(m - 3 + j) * 4096 + dp);
            a0 = fmaf(b2f((uint16_t)(v & 0xffff)), cw[dp * 4 + j], a0);
            a1 = fmaf(b2f((uint16_t)(v >> 16)),    cw[(dp + 1) * 4 + j], a1);
        }
    }
    float s0 = a0 / (1.f + __expf(-a0));
    float s1 = a1 / (1.f + __expf(-a1));
    uint32_t out = (uint32_t)f2b(s0) | ((uint32_t)f2b(s1) << 16);
    *(uint32_t*)(u + (size_t)m * DINNER + dp) = out;
}

// ---------------------------------------------------------------------------
// extract delta_raw (cols 0..63 of xdbl, fp32) -> bf16 [8192][64]
// ---------------------------------------------------------------------------
__global__ __launch_bounds__(256) void extract_dr_kernel(
    const float* __restrict__ xdbl, uint16_t* __restrict__ dr)
{
    int idx = blockIdx.x * 256 + threadIdx.x;   // 0 .. 8192*64-1
    int m = idx >> 6, r = idx & 63;
    dr[idx] = f2b(xdbl[(size_t)m * 96 + r]);
}

// ---------------------------------------------------------------------------
// selective scan + skip + gate, fused.
// thread = (b, d, n): 256 threads = 16 d x 16 n; grid (DINNER/16, BATCH)
// h_t = exp(delta*A[d][n]) * h + delta*u*B[t][n];  y = sum_n h*C[t][n]
// y16[m][d] = (y + u*D[d]) * silu(res[m][d])
// ---------------------------------------------------------------------------
__global__ __launch_bounds__(256) void scan_kernel(
    const uint16_t* __restrict__ delta16, const uint16_t* __restrict__ u16,
    const float* __restrict__ xdbl, const uint16_t* __restrict__ z16,
    const float* __restrict__ A_log, const float* __restrict__ Dvec,
    uint16_t* __restrict__ y16)
{
    int n = threadIdx.x & 15;
    int d = blockIdx.x * 16 + (threadIdx.x >> 4);
    int b = blockIdx.y;
    float a  = -__expf(A_log[d * DSTATE + n]);
    float Dd = Dvec[d];
    float h = 0.f;
    size_t mbase = (size_t)b * T_LEN;
    for (int t = 0; t < T_LEN; ++t) {
        size_t m = mbase + t;
        float delta = b2f(delta16[m * DINNER + d]);
        float uu    = b2f(u16[m * DINNER + d]);
        float Bv    = xdbl[m * 96 + 64 + n];
        float Cv    = xdbl[m * 96 + 80 + n];
        float dA = __expf(delta * a);
        h = fmaf(dA, h, delta * uu * Bv);
        float p = h * Cv;
        p += __shfl_xor(p, 1);
        p += __shfl_xor(p, 2);
        p += __shfl_xor(p, 4);
        p += __shfl_xor(p, 8);
        if (n == 0) {
            float y  = p + uu * Dd;
            float rg = b2f(z16[m * 4096 + DINNER + d]);
            float sig = 1.f / (1.f + __expf(-rg));
            y16[m * DINNER + d] = f2b(y * rg * sig);
        }
    }
}

// ---------------------------------------------------------------------------
extern "C" void kernel_launch(void* const* d_in, const int* in_sizes, int n_in,
                              void* d_out, int out_size, void* d_ws, size_t ws_size,
                              hipStream_t stream)
{
    const float* x     = (const float*)d_in[0];
    const float* W_in  = (const float*)d_in[1];
    const float* cw    = (const float*)d_in[2];
    const float* cb    = (const float*)d_in[3];
    const float* W_x   = (const float*)d_in[4];
    const float* W_dt  = (const float*)d_in[5];
    const float* b_dt  = (const float*)d_in[6];
    const float* A_log = (const float*)d_in[7];
    const float* Dv    = (const float*)d_in[8];
    const float* W_out = (const float*)d_in[9];

    char* ws = (char*)d_ws;
    size_t off = 0;
    uint16_t* xb16    = (uint16_t*)(ws + off); off += (size_t)MROWS * DMODEL * 2;   // 16.8 MB
    uint16_t* WinT    = (uint16_t*)(ws + off); off += (size_t)4096 * 1024 * 2;      //  8.4 MB
    uint16_t* WoutT   = (uint16_t*)(ws + off); off += (size_t)1024 * 2048 * 2;      //  4.2 MB
    uint16_t* WxT     = (uint16_t*)(ws + off); off += (size_t)128 * 2048 * 2;       //  0.5 MB (padded to 128 rows)
    uint16_t* WdtT    = (uint16_t*)(ws + off); off += (size_t)2048 * 64 * 2;        //  0.26 MB
    uint16_t* z16     = (uint16_t*)(ws + off); off += (size_t)MROWS * 4096 * 2;     // 67 MB (u_raw | res)
    uint16_t* u16     = (uint16_t*)(ws + off); off += (size_t)MROWS * DINNER * 2;   // 33.5 MB
    float*    xdbl    = (float*)(ws + off);    off += (size_t)MROWS * 96 * 4;       //  3.1 MB
    uint16_t* dr16    = (uint16_t*)(ws + off); off += (size_t)MROWS * 64 * 2;       //  1.0 MB
    uint16_t* delta16 = (uint16_t*)(ws + off); off += (size_t)MROWS * DINNER * 2;   // 33.5 MB
    uint16_t* y16     = (uint16_t*)(ws + off); off += (size_t)MROWS * DINNER * 2;   // 33.5 MB

    dim3 tb(32, 8);
    convert_x_kernel<<<MROWS, 256, 0, stream>>>(x, xb16);
    transpose_cvt_kernel<<<dim3(32, 128), tb, 0, stream>>>(W_in,  WinT,  1024, 4096, 4096);
    transpose_cvt_kernel<<<dim3(64, 32),  tb, 0, stream>>>(W_out, WoutT, 2048, 1024, 1024);
    transpose_cvt_kernel<<<dim3(64, 4),   tb, 0, stream>>>(W_x,   WxT,   2048, 96, 128);
    transpose_cvt_kernel<<<dim3(2, 64),   tb, 0, stream>>>(W_dt,  WdtT,  64, 2048, 2048);

    // z = X @ W_in   (8192 x 4096 x 1024)
    gemm_bt_kernel<EPI_BF16><<<dim3(64, 32), 256, 0, stream>>>(
        xb16, WinT, z16, nullptr, 4096, 1024, 4096);
    // u = silu(causal depthwise conv(z_u) + cb)
    conv_silu_kernel<<<MROWS * DMODEL / 256, 256, 0, stream>>>(z16, cw, cb, u16);
    // x_dbl = u @ W_x   (8192 x 96 x 2048)
    gemm_bt_kernel<EPI_F32G><<<dim3(64, 1), 256, 0, stream>>>(
        u16, WxT, xdbl, nullptr, 96, 2048, 96);
    // delta_raw -> bf16
    extract_dr_kernel<<<MROWS * 64 / 256, 256, 0, stream>>>(xdbl, dr16);
    // delta = softplus(delta_raw @ W_dt + b_dt)   (8192 x 2048 x 64)
    gemm_bt_kernel<EPI_SP><<<dim3(64, 16), 256, 0, stream>>>(
        dr16, WdtT, delta16, b_dt, 2048, 64, 2048);
    // selective scan + skip + gate
    scan_kernel<<<dim3(DINNER / 16, BATCH), 256, 0, stream>>>(
        delta16, u16, xdbl, z16, A_log, Dv, y16);
    // out = y @ W_out   (8192 x 1024 x 2048), remapped to (t,b,c) fp32
    gemm_bt_kernel<EPI_REMAP><<<dim3(64, 8), 256, 0, stream>>>(
        y16, WoutT, d_out, nullptr, 1024, 2048, 1024);
}

// Round 2
// 889.677 us; speedup vs baseline: 2.2181x; 2.2181x over previous
//
#include <hip/hip_runtime.h>
#include <hip/hip_bf16.h>
#include <stdint.h>

#define T_LEN   2048
#define BATCH   4
#define DMODEL  1024
#define DINNER  2048
#define DSTATE  16
#define DTRANK  64
#define MROWS   (BATCH*T_LEN)   // 8192
#define NCHUNK  8
#define CLEN    (T_LEN / NCHUNK)  // 256

typedef __bf16 bf16x8_t __attribute__((ext_vector_type(8)));
typedef float  f32x4_t  __attribute__((ext_vector_type(4)));

__device__ __forceinline__ uint16_t f2b(float f) {
    uint32_t u = __float_as_uint(f);
    u += 0x7fffu + ((u >> 16) & 1u);          // round-to-nearest-even
    return (uint16_t)(u >> 16);
}
__device__ __forceinline__ float b2f(uint16_t h) {
    return __uint_as_float(((uint32_t)h) << 16);
}

// ---------------------------------------------------------------------------
// x (t,b,c) fp32  ->  xb16 (b*T+t, c) bf16   (permute + convert)
// ---------------------------------------------------------------------------
__global__ __launch_bounds__(256) void convert_x_kernel(
    const float* __restrict__ x, uint16_t* __restrict__ xb)
{
    int tb = blockIdx.x;            // 0..8191, = t*4 + b
    int t = tb >> 2, b = tb & 3;
    int c = threadIdx.x * 4;
    const float4 v = *(const float4*)(x + ((size_t)tb) * DMODEL + c);
    uint16_t* dst = xb + ((size_t)(b * T_LEN + t)) * DMODEL + c;
    uint2 p;
    p.x = (uint32_t)f2b(v.x) | ((uint32_t)f2b(v.y) << 16);
    p.y = (uint32_t)f2b(v.z) | ((uint32_t)f2b(v.w) << 16);
    *(uint2*)dst = p;
}

// ---------------------------------------------------------------------------
// transpose + convert: src fp32 [R][C] -> dst bf16 [Cpad][R], zero-fill c>=C
// ---------------------------------------------------------------------------
__global__ __launch_bounds__(256) void transpose_cvt_kernel(
    const float* __restrict__ src, uint16_t* __restrict__ dst,
    int R, int C, int Cpad)
{
    __shared__ float tile[32][33];
    int r0 = blockIdx.x * 32;
    int c0 = blockIdx.y * 32;
    int tx = threadIdx.x, ty = threadIdx.y;
#pragma unroll
    for (int i = 0; i < 32; i += 8) {
        int r = r0 + ty + i, c = c0 + tx;
        tile[ty + i][tx] = (r < R && c < C) ? src[(size_t)r * C + c] : 0.f;
    }
    __syncthreads();
#pragma unroll
    for (int i = 0; i < 32; i += 8) {
        int dr = c0 + ty + i;   // dst row = src col
        int dc = r0 + tx;       // dst col = src row
        if (dr < Cpad && dc < R) dst[(size_t)dr * R + dc] = f2b(tile[tx][ty + i]);
    }
}

// ---------------------------------------------------------------------------
// Generic bf16 MFMA GEMM: C[M][N] = A[M][K] * Bt[N][K]^T
// ---------------------------------------------------------------------------
#define EPI_BF16  0
#define EPI_F32G  1
#define EPI_SP    2
#define EPI_REMAP 3

template <int EPI>
__global__ __launch_bounds__(256) void gemm_bt_kernel(
    const uint16_t* __restrict__ A, const uint16_t* __restrict__ Bt,
    void* __restrict__ Cout, const float* __restrict__ bias,
    int N, int K, int ldc)
{
    __shared__ uint16_t As[128 * 32];
    __shared__ uint16_t Bs[128 * 32];

    int tid = threadIdx.x;
    int bm = blockIdx.x * 128, bn = blockIdx.y * 128;

    const uint16_t* ap0 = A  + (size_t)(bm + (tid >> 2)) * K + (tid & 3) * 8;
    const uint16_t* ap1 = ap0 + (size_t)64 * K;
    const uint16_t* bp0 = Bt + (size_t)(bn + (tid >> 2)) * K + (tid & 3) * 8;
    const uint16_t* bp1 = bp0 + (size_t)64 * K;

    f32x4_t acc[4][4];
#pragma unroll
    for (int i = 0; i < 4; i++)
#pragma unroll
        for (int j = 0; j < 4; j++) acc[i][j] = (f32x4_t){0.f, 0.f, 0.f, 0.f};

    int wid = tid >> 6, lane = tid & 63;
    int wm = (wid & 1) * 64, wn = (wid >> 1) * 64;
    int lr = lane & 15, lq = lane >> 4;
    const uint16_t* Afrag = &As[(wm + lr) * 32 + lq * 8];
    const uint16_t* Bfrag = &Bs[(wn + lr) * 32 + lq * 8];

    for (int k0 = 0; k0 < K; k0 += 32) {
        uint4 a0 = *(const uint4*)ap0; uint4 a1 = *(const uint4*)ap1;
        uint4 b0 = *(const uint4*)bp0; uint4 b1 = *(const uint4*)bp1;
        ap0 += 32; ap1 += 32; bp0 += 32; bp1 += 32;
        __syncthreads();
        *(uint4*)&As[(size_t)tid * 8]         = a0;
        *(uint4*)&As[(size_t)(tid + 256) * 8] = a1;
        *(uint4*)&Bs[(size_t)tid * 8]         = b0;
        *(uint4*)&Bs[(size_t)(tid + 256) * 8] = b1;
        __syncthreads();

        bf16x8_t av[4], bv[4];
#pragma unroll
        for (int i = 0; i < 4; i++) av[i] = *(const bf16x8_t*)(Afrag + i * 512);
#pragma unroll
        for (int j = 0; j < 4; j++) bv[j] = *(const bf16x8_t*)(Bfrag + j * 512);
#pragma unroll
        for (int i = 0; i < 4; i++)
#pragma unroll
            for (int j = 0; j < 4; j++)
                acc[i][j] = __builtin_amdgcn_mfma_f32_16x16x32_bf16(
                    av[i], bv[j], acc[i][j], 0, 0, 0);
    }

#pragma unroll
    for (int i = 0; i < 4; i++) {
#pragma unroll
        for (int j = 0; j < 4; j++) {
            int col = bn + wn + j * 16 + lr;
#pragma unroll
            for (int r = 0; r < 4; r++) {
                int row = bm + wm + i * 16 + lq * 4 + r;
                float v = acc[i][j][r];
                if (EPI == EPI_BF16) {
                    ((uint16_t*)Cout)[(size_t)row * ldc + col] = f2b(v);
                } else if (EPI == EPI_F32G) {
                    if (col < N) ((float*)Cout)[(size_t)row * ldc + col] = v;
                } else if (EPI == EPI_SP) {
                    float xv = v + bias[col];
                    float sp = (xv > 15.f) ? xv : __logf(1.f + __expf(xv));
                    ((uint16_t*)Cout)[(size_t)row * ldc + col] = f2b(sp);
                } else {
                    int bb = row >> 11, tt = row & (T_LEN - 1);
                    ((float*)Cout)[((size_t)(tt * BATCH + bb)) * ldc + col] = v;
                }
            }
        }
    }
}

// ---------------------------------------------------------------------------
// depthwise causal conv (width 4) + bias + SiLU
// ---------------------------------------------------------------------------
__global__ __launch_bounds__(256) void conv_silu_kernel(
    const uint16_t* __restrict__ z, const float* __restrict__ cw,
    const float* __restrict__ cb, uint16_t* __restrict__ u)
{
    int idx = blockIdx.x * 256 + threadIdx.x;   // 0 .. 8192*1024-1
    int m  = idx >> 10;
    int dp = (idx & 1023) << 1;
    int t  = m & (T_LEN - 1);
    float a0 = cb[dp], a1 = cb[dp + 1];
#pragma unroll
    for (int j = 0; j < 4; j++) {
        int tt = t - 3 + j;
        if (tt >= 0) {
            uint32_t v = *(const uint32_t*)(z + (size_t)(m - 3 + j) * 4096 + dp);
            a0 = fmaf(b2f((uint16_t)(v & 0xffff)), cw[dp * 4 + j], a0);
            a1 = fmaf(b2f((uint16_t)(v >> 16)),    cw[(dp + 1) * 4 + j], a1);
        }
    }
    float s0 = a0 / (1.f + __expf(-a0));
    float s1 = a1 / (1.f + __expf(-a1));
    uint32_t out = (uint32_t)f2b(s0) | ((uint32_t)f2b(s1) << 16);
    *(uint32_t*)(u + (size_t)m * DINNER + dp) = out;
}

// ---------------------------------------------------------------------------
// extract delta_raw (cols 0..63 of xdbl, fp32) -> bf16 [8192][64]
// ---------------------------------------------------------------------------
__global__ __launch_bounds__(256) void extract_dr_kernel(
    const float* __restrict__ xdbl, uint16_t* __restrict__ dr)
{
    int idx = blockIdx.x * 256 + threadIdx.x;   // 0 .. 8192*64-1
    int m = idx >> 6, r = idx & 63;
    dr[idx] = f2b(xdbl[(size_t)m * 96 + r]);
}

// ---------------------------------------------------------------------------
// CHUNKED SELECTIVE SCAN.  h is affine in h0 over a chunk:
//   h_end = P*h_start + Q,  P = prod(dA), Q = scan with h_start = 0.
// pass1: per (b,d,n,chunk) compute P,Q        (parallel, 1M threads)
// pass2: serial combine over NCHUNK chunks -> per-chunk initial state H0
// pass3: re-run recurrence per chunk from H0, emit gated output y16
// All loops hand-pipelined: next-iteration loads issued before compute.
// ---------------------------------------------------------------------------
__global__ __launch_bounds__(256) void scan_part1_kernel(
    const uint16_t* __restrict__ delta16, const uint16_t* __restrict__ u16,
    const float* __restrict__ xdbl, const float* __restrict__ A_log,
    float* __restrict__ Pws, float* __restrict__ Qws)
{
    int n = threadIdx.x & 15;
    int d = blockIdx.x * 16 + (threadIdx.x >> 4);
    int b = blockIdx.y;
    int c = blockIdx.z;
    float a = -__expf(A_log[d * DSTATE + n]);
    float h = 0.f, P = 1.f;
    size_t mbase = (size_t)b * T_LEN + (size_t)c * CLEN;

    float delta = b2f(delta16[mbase * DINNER + d]);
    float uu    = b2f(u16[mbase * DINNER + d]);
    float Bv    = xdbl[mbase * 96 + 64 + n];
    for (int t = 0; t < CLEN; ++t) {
        float nd = 0.f, nu = 0.f, nB = 0.f;
        if (t + 1 < CLEN) {
            size_t m2 = mbase + t + 1;
            nd = b2f(delta16[m2 * DINNER + d]);
            nu = b2f(u16[m2 * DINNER + d]);
            nB = xdbl[m2 * 96 + 64 + n];
        }
        float dA = __expf(delta * a);
        h = fmaf(dA, h, delta * uu * Bv);
        P *= dA;
        delta = nd; uu = nu; Bv = nB;
    }
    size_t idx = ((size_t)(c * BATCH + b) * DINNER + d) * DSTATE + n;
    Pws[idx] = P;
    Qws[idx] = h;
}

__global__ __launch_bounds__(256) void scan_combine_kernel(
    const float* __restrict__ Pws, const float* __restrict__ Qws,
    float* __restrict__ H0ws)
{
    size_t i = (size_t)blockIdx.x * 256 + threadIdx.x;  // BATCH*DINNER*DSTATE
    const size_t stride = (size_t)BATCH * DINNER * DSTATE;
    float h = 0.f;
#pragma unroll
    for (int c = 0; c < NCHUNK; ++c) {
        H0ws[c * stride + i] = h;
        h = fmaf(Pws[c * stride + i], h, Qws[c * stride + i]);
    }
}

__global__ __launch_bounds__(256) void scan_part3_kernel(
    const uint16_t* __restrict__ delta16, const uint16_t* __restrict__ u16,
    const float* __restrict__ xdbl, const uint16_t* __restrict__ z16,
    const float* __restrict__ A_log, const float* __restrict__ Dvec,
    const float* __restrict__ H0ws, uint16_t* __restrict__ y16)
{
    int n = threadIdx.x & 15;
    int d = blockIdx.x * 16 + (threadIdx.x >> 4);
    int b = blockIdx.y;
    int c = blockIdx.z;
    float a  = -__expf(A_log[d * DSTATE + n]);
    float Dd = Dvec[d];
    const size_t stride = (size_t)BATCH * DINNER * DSTATE;
    float h = H0ws[c * stride + ((size_t)(b * DINNER + d) * DSTATE + n)];
    size_t mbase = (size_t)b * T_LEN + (size_t)c * CLEN;

    float delta = b2f(delta16[mbase * DINNER + d]);
    float uu    = b2f(u16[mbase * DINNER + d]);
    float Bv    = xdbl[mbase * 96 + 64 + n];
    float Cv    = xdbl[mbase * 96 + 80 + n];
    float rg    = b2f(z16[mbase * 4096 + DINNER + d]);
    for (int t = 0; t < CLEN; ++t) {
        float nd = 0.f, nu = 0.f, nB = 0.f, nC = 0.f, nr = 0.f;
        if (t + 1 < CLEN) {
            size_t m2 = mbase + t + 1;
            nd = b2f(delta16[m2 * DINNER + d]);
            nu = b2f(u16[m2 * DINNER + d]);
            nB = xdbl[m2 * 96 + 64 + n];
            nC = xdbl[m2 * 96 + 80 + n];
            nr = b2f(z16[m2 * 4096 + DINNER + d]);
        }
        float dA = __expf(delta * a);
        h = fmaf(dA, h, delta * uu * Bv);
        float p = h * Cv;
        p += __shfl_xor(p, 1);
        p += __shfl_xor(p, 2);
        p += __shfl_xor(p, 4);
        p += __shfl_xor(p, 8);
        if (n == 0) {
            size_t m = mbase + t;
            float y   = p + uu * Dd;
            float sig = 1.f / (1.f + __expf(-rg));
            y16[m * DINNER + d] = f2b(y * rg * sig);
        }
        delta = nd; uu = nu; Bv = nB; Cv = nC; rg = nr;
    }
}

// ---------------------------------------------------------------------------
extern "C" void kernel_launch(void* const* d_in, const int* in_sizes, int n_in,
                              void* d_out, int out_size, void* d_ws, size_t ws_size,
                              hipStream_t stream)
{
    const float* x     = (const float*)d_in[0];
    const float* W_in  = (const float*)d_in[1];
    const float* cw    = (const float*)d_in[2];
    const float* cb    = (const float*)d_in[3];
    const float* W_x   = (const float*)d_in[4];
    const float* W_dt  = (const float*)d_in[5];
    const float* b_dt  = (const float*)d_in[6];
    const float* A_log = (const float*)d_in[7];
    const float* Dv    = (const float*)d_in[8];
    const float* W_out = (const float*)d_in[9];

    char* ws = (char*)d_ws;
    size_t off = 0;
    uint16_t* xb16    = (uint16_t*)(ws + off); off += (size_t)MROWS * DMODEL * 2;   // 16.8 MB
    uint16_t* WinT    = (uint16_t*)(ws + off); off += (size_t)4096 * 1024 * 2;      //  8.4 MB
    uint16_t* WoutT   = (uint16_t*)(ws + off); off += (size_t)1024 * 2048 * 2;      //  4.2 MB
    uint16_t* WxT     = (uint16_t*)(ws + off); off += (size_t)128 * 2048 * 2;       //  0.5 MB
    uint16_t* WdtT    = (uint16_t*)(ws + off); off += (size_t)2048 * 64 * 2;        //  0.26 MB
    uint16_t* z16     = (uint16_t*)(ws + off); off += (size_t)MROWS * 4096 * 2;     // 67 MB (u_raw | res)
    uint16_t* u16     = (uint16_t*)(ws + off); off += (size_t)MROWS * DINNER * 2;   // 33.5 MB
    float*    xdbl    = (float*)(ws + off);    off += (size_t)MROWS * 96 * 4;       //  3.1 MB
    uint16_t* dr16    = (uint16_t*)(ws + off); off += (size_t)MROWS * 64 * 2;       //  1.0 MB
    uint16_t* delta16 = (uint16_t*)(ws + off); off += (size_t)MROWS * DINNER * 2;   // 33.5 MB
    uint16_t* y16     = (uint16_t*)(ws + off); off += (size_t)MROWS * DINNER * 2;   // 33.5 MB

    // Scan scratch aliases xb16 (dead after in_proj GEMM): 3 x 4 MB <= 16.8 MB
    float* Pws  = (float*)xb16;
    float* Qws  = Pws + (size_t)NCHUNK * BATCH * DINNER * DSTATE;
    float* H0ws = Qws + (size_t)NCHUNK * BATCH * DINNER * DSTATE;

    dim3 tb(32, 8);
    convert_x_kernel<<<MROWS, 256, 0, stream>>>(x, xb16);
    transpose_cvt_kernel<<<dim3(32, 128), tb, 0, stream>>>(W_in,  WinT,  1024, 4096, 4096);
    transpose_cvt_kernel<<<dim3(64, 32),  tb, 0, stream>>>(W_out, WoutT, 2048, 1024, 1024);
    transpose_cvt_kernel<<<dim3(64, 4),   tb, 0, stream>>>(W_x,   WxT,   2048, 96, 128);
    transpose_cvt_kernel<<<dim3(2, 64),   tb, 0, stream>>>(W_dt,  WdtT,  64, 2048, 2048);

    // z = X @ W_in   (8192 x 4096 x 1024)
    gemm_bt_kernel<EPI_BF16><<<dim3(64, 32), 256, 0, stream>>>(
        xb16, WinT, z16, nullptr, 4096, 1024, 4096);
    // u = silu(causal depthwise conv(z_u) + cb)
    conv_silu_kernel<<<MROWS * DMODEL / 256, 256, 0, stream>>>(z16, cw, cb, u16);
    // x_dbl = u @ W_x   (8192 x 96 x 2048)
    gemm_bt_kernel<EPI_F32G><<<dim3(64, 1), 256, 0, stream>>>(
        u16, WxT, xdbl, nullptr, 96, 2048, 96);
    // delta_raw -> bf16
    extract_dr_kernel<<<MROWS * 64 / 256, 256, 0, stream>>>(xdbl, dr16);
    // delta = softplus(delta_raw @ W_dt + b_dt)   (8192 x 2048 x 64)
    gemm_bt_kernel<EPI_SP><<<dim3(64, 16), 256, 0, stream>>>(
        dr16, WdtT, delta16, b_dt, 2048, 64, 2048);

    // chunked selective scan (replaces the 1527 us serial scan)
    scan_part1_kernel<<<dim3(DINNER / 16, BATCH, NCHUNK), 256, 0, stream>>>(
        delta16, u16, xdbl, A_log, Pws, Qws);
    scan_combine_kernel<<<BATCH * DINNER * DSTATE / 256, 256, 0, stream>>>(
        Pws, Qws, H0ws);
    scan_part3_kernel<<<dim3(DINNER / 16, BATCH, NCHUNK), 256, 0, stream>>>(
        delta16, u16, xdbl, z16, A_log, Dv, H0ws, y16);

    // out = y @ W_out   (8192 x 1024 x 2048), remapped to (t,b,c) fp32
    gemm_bt_kernel<EPI_REMAP><<<dim3(64, 8), 256, 0, stream>>>(
        y16, WoutT, d_out, nullptr, 1024, 2048, 1024);
}

// Round 3
// 614.886 us; speedup vs baseline: 3.2094x; 1.4469x over previous
//
#include <hip/hip_runtime.h>
#include <hip/hip_bf16.h>
#include <stdint.h>

#define T_LEN   2048
#define BATCH   4
#define DMODEL  1024
#define DINNER  2048
#define DSTATE  16
#define DTRANK  64
#define MROWS   (BATCH*T_LEN)   // 8192
#define NCHUNK  16
#define CLEN    (T_LEN / NCHUNK)  // 128

typedef __bf16 bf16x8_t __attribute__((ext_vector_type(8)));
typedef float  f32x4_t  __attribute__((ext_vector_type(4)));

__device__ __forceinline__ uint16_t f2b(float f) {
    uint32_t u = __float_as_uint(f);
    u += 0x7fffu + ((u >> 16) & 1u);          // round-to-nearest-even
    return (uint16_t)(u >> 16);
}
__device__ __forceinline__ float b2f(uint16_t h) {
    return __uint_as_float(((uint32_t)h) << 16);
}

// ---------------------------------------------------------------------------
// x (t,b,c) fp32  ->  xb16 (b*T+t, c) bf16   (permute + convert)
// ---------------------------------------------------------------------------
__global__ __launch_bounds__(256) void convert_x_kernel(
    const float* __restrict__ x, uint16_t* __restrict__ xb)
{
    int tb = blockIdx.x;            // 0..8191, = t*4 + b
    int t = tb >> 2, b = tb & 3;
    int c = threadIdx.x * 4;
    const float4 v = *(const float4*)(x + ((size_t)tb) * DMODEL + c);
    uint16_t* dst = xb + ((size_t)(b * T_LEN + t)) * DMODEL + c;
    uint2 p;
    p.x = (uint32_t)f2b(v.x) | ((uint32_t)f2b(v.y) << 16);
    p.y = (uint32_t)f2b(v.z) | ((uint32_t)f2b(v.w) << 16);
    *(uint2*)dst = p;
}

// ---------------------------------------------------------------------------
// transpose + convert: src fp32 [R][C] -> dst bf16 [Cpad][R], zero-fill c>=C
// ---------------------------------------------------------------------------
__global__ __launch_bounds__(256) void transpose_cvt_kernel(
    const float* __restrict__ src, uint16_t* __restrict__ dst,
    int R, int C, int Cpad)
{
    __shared__ float tile[32][33];
    int r0 = blockIdx.x * 32;
    int c0 = blockIdx.y * 32;
    int tx = threadIdx.x, ty = threadIdx.y;
#pragma unroll
    for (int i = 0; i < 32; i += 8) {
        int r = r0 + ty + i, c = c0 + tx;
        tile[ty + i][tx] = (r < R && c < C) ? src[(size_t)r * C + c] : 0.f;
    }
    __syncthreads();
#pragma unroll
    for (int i = 0; i < 32; i += 8) {
        int dr = c0 + ty + i;   // dst row = src col
        int dc = r0 + tx;       // dst col = src row
        if (dr < Cpad && dc < R) dst[(size_t)dr * R + dc] = f2b(tile[tx][ty + i]);
    }
}

// ---------------------------------------------------------------------------
// Generic bf16 MFMA GEMM: C[M][N] = A[M][K] * Bt[N][K]^T
// ---------------------------------------------------------------------------
#define EPI_BF16  0
#define EPI_F32G  1
#define EPI_SP    2
#define EPI_REMAP 3

template <int EPI>
__global__ __launch_bounds__(256) void gemm_bt_kernel(
    const uint16_t* __restrict__ A, const uint16_t* __restrict__ Bt,
    void* __restrict__ Cout, const float* __restrict__ bias,
    int N, int K, int ldc)
{
    __shared__ uint16_t As[128 * 32];
    __shared__ uint16_t Bs[128 * 32];

    int tid = threadIdx.x;
    int bm = blockIdx.x * 128, bn = blockIdx.y * 128;

    const uint16_t* ap0 = A  + (size_t)(bm + (tid >> 2)) * K + (tid & 3) * 8;
    const uint16_t* ap1 = ap0 + (size_t)64 * K;
    const uint16_t* bp0 = Bt + (size_t)(bn + (tid >> 2)) * K + (tid & 3) * 8;
    const uint16_t* bp1 = bp0 + (size_t)64 * K;

    f32x4_t acc[4][4];
#pragma unroll
    for (int i = 0; i < 4; i++)
#pragma unroll
        for (int j = 0; j < 4; j++) acc[i][j] = (f32x4_t){0.f, 0.f, 0.f, 0.f};

    int wid = tid >> 6, lane = tid & 63;
    int wm = (wid & 1) * 64, wn = (wid >> 1) * 64;
    int lr = lane & 15, lq = lane >> 4;
    const uint16_t* Afrag = &As[(wm + lr) * 32 + lq * 8];
    const uint16_t* Bfrag = &Bs[(wn + lr) * 32 + lq * 8];

    for (int k0 = 0; k0 < K; k0 += 32) {
        uint4 a0 = *(const uint4*)ap0; uint4 a1 = *(const uint4*)ap1;
        uint4 b0 = *(const uint4*)bp0; uint4 b1 = *(const uint4*)bp1;
        ap0 += 32; ap1 += 32; bp0 += 32; bp1 += 32;
        __syncthreads();
        *(uint4*)&As[(size_t)tid * 8]         = a0;
        *(uint4*)&As[(size_t)(tid + 256) * 8] = a1;
        *(uint4*)&Bs[(size_t)tid * 8]         = b0;
        *(uint4*)&Bs[(size_t)(tid + 256) * 8] = b1;
        __syncthreads();

        bf16x8_t av[4], bv[4];
#pragma unroll
        for (int i = 0; i < 4; i++) av[i] = *(const bf16x8_t*)(Afrag + i * 512);
#pragma unroll
        for (int j = 0; j < 4; j++) bv[j] = *(const bf16x8_t*)(Bfrag + j * 512);
#pragma unroll
        for (int i = 0; i < 4; i++)
#pragma unroll
            for (int j = 0; j < 4; j++)
                acc[i][j] = __builtin_amdgcn_mfma_f32_16x16x32_bf16(
                    av[i], bv[j], acc[i][j], 0, 0, 0);
    }

#pragma unroll
    for (int i = 0; i < 4; i++) {
#pragma unroll
        for (int j = 0; j < 4; j++) {
            int col = bn + wn + j * 16 + lr;
#pragma unroll
            for (int r = 0; r < 4; r++) {
                int row = bm + wm + i * 16 + lq * 4 + r;
                float v = acc[i][j][r];
                if (EPI == EPI_BF16) {
                    ((uint16_t*)Cout)[(size_t)row * ldc + col] = f2b(v);
                } else if (EPI == EPI_F32G) {
                    if (col < N) ((float*)Cout)[(size_t)row * ldc + col] = v;
                } else if (EPI == EPI_SP) {
                    float xv = v + bias[col];
                    float sp = (xv > 15.f) ? xv : __logf(1.f + __expf(xv));
                    ((uint16_t*)Cout)[(size_t)row * ldc + col] = f2b(sp);
                } else {
                    int bb = row >> 11, tt = row & (T_LEN - 1);
                    ((float*)Cout)[((size_t)(tt * BATCH + bb)) * ldc + col] = v;
                }
            }
        }
    }
}

// ---------------------------------------------------------------------------
// depthwise causal conv (width 4) + bias + SiLU
// ---------------------------------------------------------------------------
__global__ __launch_bounds__(256) void conv_silu_kernel(
    const uint16_t* __restrict__ z, const float* __restrict__ cw,
    const float* __restrict__ cb, uint16_t* __restrict__ u)
{
    int idx = blockIdx.x * 256 + threadIdx.x;   // 0 .. 8192*1024-1
    int m  = idx >> 10;
    int dp = (idx & 1023) << 1;
    int t  = m & (T_LEN - 1);
    float a0 = cb[dp], a1 = cb[dp + 1];
#pragma unroll
    for (int j = 0; j < 4; j++) {
        int tt = t - 3 + j;
        if (tt >= 0) {
            uint32_t v = *(const uint32_t*)(z + (size_t)(m - 3 + j) * 4096 + dp);
            a0 = fmaf(b2f((uint16_t)(v & 0xffff)), cw[dp * 4 + j], a0);
            a1 = fmaf(b2f((uint16_t)(v >> 16)),    cw[(dp + 1) * 4 + j], a1);
        }
    }
    float s0 = a0 / (1.f + __expf(-a0));
    float s1 = a1 / (1.f + __expf(-a1));
    uint32_t out = (uint32_t)f2b(s0) | ((uint32_t)f2b(s1) << 16);
    *(uint32_t*)(u + (size_t)m * DINNER + dp) = out;
}

// ---------------------------------------------------------------------------
// extract delta_raw (cols 0..63 of xdbl, fp32) -> bf16 [8192][64]
// ---------------------------------------------------------------------------
__global__ __launch_bounds__(256) void extract_dr_kernel(
    const float* __restrict__ xdbl, uint16_t* __restrict__ dr)
{
    int idx = blockIdx.x * 256 + threadIdx.x;   // 0 .. 8192*64-1
    int m = idx >> 6, r = idx & 63;
    dr[idx] = f2b(xdbl[(size_t)m * 96 + r]);
}

// ---------------------------------------------------------------------------
// CHUNKED SELECTIVE SCAN, one thread = (b, d, chunk), ALL 16 n-states in regs.
//   - no shuffles: n-reduction is 16 in-register FMAs
//   - no redundant loads: delta/u/res loaded once per (d,t), coalesced 2B
//   - B[16]/C[16]: block-uniform float4 loads (HW broadcast)
//   - dA = exp2(delta * (-exp(A_log)*log2e)) : single v_exp_f32 per state
// pass1: per-chunk P = prod(dA) (16 vals), Q = scan from h0=0
// pass2: in-place combine, H0 chunk-starts overwrite P
// pass3: re-scan from H0, emit gated y16 (every thread stores its own d)
// ---------------------------------------------------------------------------
#define LOG2E 1.44269504088896340736f

__global__ __launch_bounds__(256) void scan_part1_kernel(
    const uint16_t* __restrict__ delta16, const uint16_t* __restrict__ u16,
    const float* __restrict__ xdbl, const float* __restrict__ A_log,
    float* __restrict__ Pws, float* __restrict__ Qws)
{
    int d = blockIdx.x * 256 + threadIdx.x;
    int b = blockIdx.y;
    int c = blockIdx.z;
    float ae[DSTATE];
#pragma unroll
    for (int n = 0; n < DSTATE; ++n)
        ae[n] = -__expf(A_log[d * DSTATE + n]) * LOG2E;
    float h[DSTATE], P[DSTATE];
#pragma unroll
    for (int n = 0; n < DSTATE; ++n) { h[n] = 0.f; P[n] = 1.f; }
    size_t mbase = (size_t)b * T_LEN + (size_t)c * CLEN;

#pragma unroll 2
    for (int t = 0; t < CLEN; ++t) {
        size_t m = mbase + t;
        float delta = b2f(delta16[m * DINNER + d]);
        float du    = delta * b2f(u16[m * DINNER + d]);
        float Bv[DSTATE];
        *(float4*)&Bv[0]  = *(const float4*)(xdbl + m * 96 + 64);
        *(float4*)&Bv[4]  = *(const float4*)(xdbl + m * 96 + 68);
        *(float4*)&Bv[8]  = *(const float4*)(xdbl + m * 96 + 72);
        *(float4*)&Bv[12] = *(const float4*)(xdbl + m * 96 + 76);
#pragma unroll
        for (int n = 0; n < DSTATE; ++n) {
            float w = __builtin_amdgcn_exp2f(delta * ae[n]);
            h[n] = fmaf(w, h[n], du * Bv[n]);
            P[n] *= w;
        }
    }
    float* Pp = Pws + (((size_t)c * BATCH + b) * DINNER + d) * DSTATE;
    float* Qp = Qws + (((size_t)c * BATCH + b) * DINNER + d) * DSTATE;
#pragma unroll
    for (int n = 0; n < DSTATE; n += 4) {
        *(float4*)(Pp + n) = *(float4*)&P[n];
        *(float4*)(Qp + n) = *(float4*)&h[n];
    }
}

// in-place: H0 for chunk c overwrites Pws[c]
__global__ __launch_bounds__(256) void scan_combine_kernel(
    float* __restrict__ Pws, const float* __restrict__ Qws)
{
    size_t i = (size_t)blockIdx.x * 256 + threadIdx.x;  // BATCH*DINNER*DSTATE
    const size_t stride = (size_t)BATCH * DINNER * DSTATE;
    float h = 0.f;
#pragma unroll
    for (int c = 0; c < NCHUNK; ++c) {
        float P = Pws[c * stride + i];
        float Q = Qws[c * stride + i];
        Pws[c * stride + i] = h;        // chunk-c initial state
        h = fmaf(P, h, Q);
    }
}

__global__ __launch_bounds__(256) void scan_part3_kernel(
    const uint16_t* __restrict__ delta16, const uint16_t* __restrict__ u16,
    const float* __restrict__ xdbl, const uint16_t* __restrict__ z16,
    const float* __restrict__ A_log, const float* __restrict__ Dvec,
    const float* __restrict__ H0ws, uint16_t* __restrict__ y16)
{
    int d = blockIdx.x * 256 + threadIdx.x;
    int b = blockIdx.y;
    int c = blockIdx.z;
    float ae[DSTATE];
#pragma unroll
    for (int n = 0; n < DSTATE; ++n)
        ae[n] = -__expf(A_log[d * DSTATE + n]) * LOG2E;
    float Dd = Dvec[d];
    float h[DSTATE];
    const float* H0p = H0ws + (((size_t)c * BATCH + b) * DINNER + d) * DSTATE;
#pragma unroll
    for (int n = 0; n < DSTATE; n += 4)
        *(float4*)&h[n] = *(const float4*)(H0p + n);
    size_t mbase = (size_t)b * T_LEN + (size_t)c * CLEN;

#pragma unroll 2
    for (int t = 0; t < CLEN; ++t) {
        size_t m = mbase + t;
        float delta = b2f(delta16[m * DINNER + d]);
        float uu    = b2f(u16[m * DINNER + d]);
        float rg    = b2f(z16[m * 4096 + DINNER + d]);
        float du    = delta * uu;
        float Bv[DSTATE], Cv[DSTATE];
        *(float4*)&Bv[0]  = *(const float4*)(xdbl + m * 96 + 64);
        *(float4*)&Bv[4]  = *(const float4*)(xdbl + m * 96 + 68);
        *(float4*)&Bv[8]  = *(const float4*)(xdbl + m * 96 + 72);
        *(float4*)&Bv[12] = *(const float4*)(xdbl + m * 96 + 76);
        *(float4*)&Cv[0]  = *(const float4*)(xdbl + m * 96 + 80);
        *(float4*)&Cv[4]  = *(const float4*)(xdbl + m * 96 + 84);
        *(float4*)&Cv[8]  = *(const float4*)(xdbl + m * 96 + 88);
        *(float4*)&Cv[12] = *(const float4*)(xdbl + m * 96 + 92);
        float y = 0.f;
#pragma unroll
        for (int n = 0; n < DSTATE; ++n) {
            float w = __builtin_amdgcn_exp2f(delta * ae[n]);
            h[n] = fmaf(w, h[n], du * Bv[n]);
            y = fmaf(h[n], Cv[n], y);
        }
        y = fmaf(uu, Dd, y);
        float sig = 1.f / (1.f + __expf(-rg));
        y16[m * DINNER + d] = f2b(y * rg * sig);
    }
}

// ---------------------------------------------------------------------------
extern "C" void kernel_launch(void* const* d_in, const int* in_sizes, int n_in,
                              void* d_out, int out_size, void* d_ws, size_t ws_size,
                              hipStream_t stream)
{
    const float* x     = (const float*)d_in[0];
    const float* W_in  = (const float*)d_in[1];
    const float* cw    = (const float*)d_in[2];
    const float* cb    = (const float*)d_in[3];
    const float* W_x   = (const float*)d_in[4];
    const float* W_dt  = (const float*)d_in[5];
    const float* b_dt  = (const float*)d_in[6];
    const float* A_log = (const float*)d_in[7];
    const float* Dv    = (const float*)d_in[8];
    const float* W_out = (const float*)d_in[9];

    char* ws = (char*)d_ws;
    size_t off = 0;
    uint16_t* xb16    = (uint16_t*)(ws + off); off += (size_t)MROWS * DMODEL * 2;   // 16.8 MB
    uint16_t* WinT    = (uint16_t*)(ws + off); off += (size_t)4096 * 1024 * 2;      //  8.4 MB
    uint16_t* WoutT   = (uint16_t*)(ws + off); off += (size_t)1024 * 2048 * 2;      //  4.2 MB
    uint16_t* WxT     = (uint16_t*)(ws + off); off += (size_t)128 * 2048 * 2;       //  0.5 MB
    uint16_t* WdtT    = (uint16_t*)(ws + off); off += (size_t)2048 * 64 * 2;        //  0.26 MB
    uint16_t* z16     = (uint16_t*)(ws + off); off += (size_t)MROWS * 4096 * 2;     // 67 MB (u_raw | res)
    uint16_t* u16     = (uint16_t*)(ws + off); off += (size_t)MROWS * DINNER * 2;   // 33.5 MB
    float*    xdbl    = (float*)(ws + off);    off += (size_t)MROWS * 96 * 4;       //  3.1 MB
    uint16_t* dr16    = (uint16_t*)(ws + off); off += (size_t)MROWS * 64 * 2;       //  1.0 MB
    uint16_t* delta16 = (uint16_t*)(ws + off); off += (size_t)MROWS * DINNER * 2;   // 33.5 MB
    uint16_t* y16     = (uint16_t*)(ws + off); off += (size_t)MROWS * DINNER * 2;   // 33.5 MB

    // Scan scratch aliases xb16 (dead after in_proj GEMM):
    // P + Q = 2 * NCHUNK*BATCH*DINNER*DSTATE*4 = 16.8 MB == sizeof(xb16). H0 is in-place in P.
    float* Pws = (float*)xb16;
    float* Qws = Pws + (size_t)NCHUNK * BATCH * DINNER * DSTATE;

    dim3 tb(32, 8);
    convert_x_kernel<<<MROWS, 256, 0, stream>>>(x, xb16);
    transpose_cvt_kernel<<<dim3(32, 128), tb, 0, stream>>>(W_in,  WinT,  1024, 4096, 4096);
    transpose_cvt_kernel<<<dim3(64, 32),  tb, 0, stream>>>(W_out, WoutT, 2048, 1024, 1024);
    transpose_cvt_kernel<<<dim3(64, 4),   tb, 0, stream>>>(W_x,   WxT,   2048, 96, 128);
    transpose_cvt_kernel<<<dim3(2, 64),   tb, 0, stream>>>(W_dt,  WdtT,  64, 2048, 2048);

    // z = X @ W_in   (8192 x 4096 x 1024)
    gemm_bt_kernel<EPI_BF16><<<dim3(64, 32), 256, 0, stream>>>(
        xb16, WinT, z16, nullptr, 4096, 1024, 4096);
    // u = silu(causal depthwise conv(z_u) + cb)
    conv_silu_kernel<<<MROWS * DMODEL / 256, 256, 0, stream>>>(z16, cw, cb, u16);
    // x_dbl = u @ W_x   (8192 x 96 x 2048)
    gemm_bt_kernel<EPI_F32G><<<dim3(64, 1), 256, 0, stream>>>(
        u16, WxT, xdbl, nullptr, 96, 2048, 96);
    // delta_raw -> bf16
    extract_dr_kernel<<<MROWS * 64 / 256, 256, 0, stream>>>(xdbl, dr16);
    // delta = softplus(delta_raw @ W_dt + b_dt)   (8192 x 2048 x 64)
    gemm_bt_kernel<EPI_SP><<<dim3(64, 16), 256, 0, stream>>>(
        dr16, WdtT, delta16, b_dt, 2048, 64, 2048);

    // chunked selective scan, register-resident states
    scan_part1_kernel<<<dim3(DINNER / 256, BATCH, NCHUNK), 256, 0, stream>>>(
        delta16, u16, xdbl, A_log, Pws, Qws);
    scan_combine_kernel<<<BATCH * DINNER * DSTATE / 256, 256, 0, stream>>>(
        Pws, Qws);
    scan_part3_kernel<<<dim3(DINNER / 256, BATCH, NCHUNK), 256, 0, stream>>>(
        delta16, u16, xdbl, z16, A_log, Dv, Pws, y16);

    // out = y @ W_out   (8192 x 1024 x 2048), remapped to (t,b,c) fp32
    gemm_bt_kernel<EPI_REMAP><<<dim3(64, 8), 256, 0, stream>>>(
        y16, WoutT, d_out, nullptr, 1024, 2048, 1024);
}

// Round 4
// 482.064 us; speedup vs baseline: 4.0936x; 1.2755x over previous
//
#include <hip/hip_runtime.h>
#include <hip/hip_bf16.h>
#include <stdint.h>

#define T_LEN   2048
#define BATCH   4
#define DMODEL  1024
#define DINNER  2048
#define DSTATE  16
#define DTRANK  64
#define MROWS   (BATCH*T_LEN)   // 8192
#define NCHUNK  16
#define CLEN    (T_LEN / NCHUNK)  // 128

typedef __bf16 bf16x8_t __attribute__((ext_vector_type(8)));
typedef float  f32x4_t  __attribute__((ext_vector_type(4)));

__device__ __forceinline__ uint16_t f2b(float f) {
    uint32_t u = __float_as_uint(f);
    u += 0x7fffu + ((u >> 16) & 1u);          // round-to-nearest-even
    return (uint16_t)(u >> 16);
}
__device__ __forceinline__ float b2f(uint16_t h) {
    return __uint_as_float(((uint32_t)h) << 16);
}

// async global->LDS, 16B per lane (m97 recipe: LDS dest must be
// wave-uniform base + lane*16, which As[tid*8] satisfies)
__device__ __forceinline__ void gload16(const void* g, void* l) {
    __builtin_amdgcn_global_load_lds(
        (const __attribute__((address_space(1))) void*)g,
        (__attribute__((address_space(3))) void*)l, 16, 0, 0);
}

// ---------------------------------------------------------------------------
// x (t,b,c) fp32  ->  xb16 (b*T+t, c) bf16   (permute + convert)
// ---------------------------------------------------------------------------
__global__ __launch_bounds__(256) void convert_x_kernel(
    const float* __restrict__ x, uint16_t* __restrict__ xb)
{
    int tb = blockIdx.x;            // 0..8191, = t*4 + b
    int t = tb >> 2, b = tb & 3;
    int c = threadIdx.x * 4;
    const float4 v = *(const float4*)(x + ((size_t)tb) * DMODEL + c);
    uint16_t* dst = xb + ((size_t)(b * T_LEN + t)) * DMODEL + c;
    uint2 p;
    p.x = (uint32_t)f2b(v.x) | ((uint32_t)f2b(v.y) << 16);
    p.y = (uint32_t)f2b(v.z) | ((uint32_t)f2b(v.w) << 16);
    *(uint2*)dst = p;
}

// ---------------------------------------------------------------------------
// transpose + convert: src fp32 [R][C] -> dst bf16 [Cpad][R], zero-fill c>=C
// ---------------------------------------------------------------------------
__global__ __launch_bounds__(256) void transpose_cvt_kernel(
    const float* __restrict__ src, uint16_t* __restrict__ dst,
    int R, int C, int Cpad)
{
    __shared__ float tile[32][33];
    int r0 = blockIdx.x * 32;
    int c0 = blockIdx.y * 32;
    int tx = threadIdx.x, ty = threadIdx.y;
#pragma unroll
    for (int i = 0; i < 32; i += 8) {
        int r = r0 + ty + i, c = c0 + tx;
        tile[ty + i][tx] = (r < R && c < C) ? src[(size_t)r * C + c] : 0.f;
    }
    __syncthreads();
#pragma unroll
    for (int i = 0; i < 32; i += 8) {
        int dr = c0 + ty + i;   // dst row = src col
        int dc = r0 + tx;       // dst col = src row
        if (dr < Cpad && dc < R) dst[(size_t)dr * R + dc] = f2b(tile[tx][ty + i]);
    }
}

// ---------------------------------------------------------------------------
// Generic bf16 MFMA GEMM: C[M][N] = A[M][K] * Bt[N][K]^T
// global_load_lds width-16 staging (m97 structure)
// ---------------------------------------------------------------------------
#define EPI_BF16  0
#define EPI_F32G  1
#define EPI_SP    2
#define EPI_REMAP 3

template <int EPI, bool SPLITK>
__global__ __launch_bounds__(256) void gemm_bt_kernel(
    const uint16_t* __restrict__ A, const uint16_t* __restrict__ Bt,
    void* __restrict__ CoutBase, const float* __restrict__ bias,
    int N, int K, int ldc, int ksplit)
{
    __shared__ uint16_t As[128 * 32];
    __shared__ uint16_t Bs[128 * 32];

    int tid = threadIdx.x;
    int bm = blockIdx.x * 128, bn = blockIdx.y * 128;
    int kbeg = SPLITK ? blockIdx.z * ksplit : 0;
    int kend = SPLITK ? kbeg + ksplit : K;
    void* Cout = SPLITK
        ? (void*)((float*)CoutBase + (size_t)blockIdx.z * MROWS * ldc)
        : CoutBase;

    const uint16_t* ap0 = A  + (size_t)(bm + (tid >> 2)) * K + kbeg + (tid & 3) * 8;
    const uint16_t* ap1 = ap0 + (size_t)64 * K;
    const uint16_t* bp0 = Bt + (size_t)(bn + (tid >> 2)) * K + kbeg + (tid & 3) * 8;
    const uint16_t* bp1 = bp0 + (size_t)64 * K;

    f32x4_t acc[4][4];
#pragma unroll
    for (int i = 0; i < 4; i++)
#pragma unroll
        for (int j = 0; j < 4; j++) acc[i][j] = (f32x4_t){0.f, 0.f, 0.f, 0.f};

    int wid = tid >> 6, lane = tid & 63;
    int wm = (wid & 1) * 64, wn = (wid >> 1) * 64;
    int lr = lane & 15, lq = lane >> 4;
    const uint16_t* Afrag = &As[(wm + lr) * 32 + lq * 8];
    const uint16_t* Bfrag = &Bs[(wn + lr) * 32 + lq * 8];

    for (int k0 = kbeg; k0 < kend; k0 += 32) {
        __syncthreads();                       // LDS safe to overwrite
        gload16(ap0, &As[(size_t)tid * 8]);
        gload16(ap1, &As[(size_t)(tid + 256) * 8]);
        gload16(bp0, &Bs[(size_t)tid * 8]);
        gload16(bp1, &Bs[(size_t)(tid + 256) * 8]);
        ap0 += 32; ap1 += 32; bp0 += 32; bp1 += 32;
        __syncthreads();                       // drains vmcnt (async LDS stores)

        bf16x8_t av[4], bv[4];
#pragma unroll
        for (int i = 0; i < 4; i++) av[i] = *(const bf16x8_t*)(Afrag + i * 512);
#pragma unroll
        for (int j = 0; j < 4; j++) bv[j] = *(const bf16x8_t*)(Bfrag + j * 512);
#pragma unroll
        for (int i = 0; i < 4; i++)
#pragma unroll
            for (int j = 0; j < 4; j++)
                acc[i][j] = __builtin_amdgcn_mfma_f32_16x16x32_bf16(
                    av[i], bv[j], acc[i][j], 0, 0, 0);
    }

#pragma unroll
    for (int i = 0; i < 4; i++) {
#pragma unroll
        for (int j = 0; j < 4; j++) {
            int col = bn + wn + j * 16 + lr;
#pragma unroll
            for (int r = 0; r < 4; r++) {
                int row = bm + wm + i * 16 + lq * 4 + r;
                float v = acc[i][j][r];
                if (EPI == EPI_BF16) {
                    ((uint16_t*)Cout)[(size_t)row * ldc + col] = f2b(v);
                } else if (EPI == EPI_F32G) {
                    if (col < N) ((float*)Cout)[(size_t)row * ldc + col] = v;
                } else if (EPI == EPI_SP) {
                    float xv = v + bias[col];
                    float sp = (xv > 15.f) ? xv : __logf(1.f + __expf(xv));
                    ((uint16_t*)Cout)[(size_t)row * ldc + col] = f2b(sp);
                } else {
                    int bb = row >> 11, tt = row & (T_LEN - 1);
                    ((float*)Cout)[((size_t)(tt * BATCH + bb)) * ldc + col] = v;
                }
            }
        }
    }
}

// ---------------------------------------------------------------------------
// depthwise causal conv (width 4) + bias + SiLU — register sliding window.
// thread = 8 cols x CROWS rows: per row ONE 16B load + ONE 16B store.
// batch boundary only at chunk start (CROWS | T_LEN), zero-preload there.
// ---------------------------------------------------------------------------
#define CROWS 16

__global__ __launch_bounds__(256) void conv_silu_kernel(
    const uint16_t* __restrict__ z, const float* __restrict__ cw,
    const float* __restrict__ cb, uint16_t* __restrict__ u)
{
    int c0 = threadIdx.x * 8;           // 0..2040
    int m0 = blockIdx.x * CROWS;

    float w[8][4], bias[8];
#pragma unroll
    for (int c = 0; c < 8; ++c)
        *(float4*)w[c] = *(const float4*)(cw + (size_t)(c0 + c) * 4);
    *(float4*)&bias[0] = *(const float4*)(cb + c0);
    *(float4*)&bias[4] = *(const float4*)(cb + c0 + 4);

    // window slots: row m lives in slot (m & 3)
    float fw[4][8];
    bool seqstart = (m0 & (T_LEN - 1)) == 0;
#pragma unroll
    for (int j = 0; j < 3; ++j) {
        int m = m0 - 3 + j;             // slot (m0+1+j)&3 = j+1  (m0%4==0)
        if (seqstart) {
#pragma unroll
            for (int c = 0; c < 8; ++c) fw[j + 1][c] = 0.f;
        } else {
            uint4 v = *(const uint4*)(z + (size_t)m * 4096 + c0);
            fw[j + 1][0] = b2f((uint16_t)(v.x & 0xffff)); fw[j + 1][1] = b2f((uint16_t)(v.x >> 16));
            fw[j + 1][2] = b2f((uint16_t)(v.y & 0xffff)); fw[j + 1][3] = b2f((uint16_t)(v.y >> 16));
            fw[j + 1][4] = b2f((uint16_t)(v.z & 0xffff)); fw[j + 1][5] = b2f((uint16_t)(v.z >> 16));
            fw[j + 1][6] = b2f((uint16_t)(v.w & 0xffff)); fw[j + 1][7] = b2f((uint16_t)(v.w >> 16));
        }
    }

#pragma unroll
    for (int t = 0; t < CROWS; ++t) {
        int m = m0 + t;
        int s = t & 3;                  // slot for row m
        uint4 v = *(const uint4*)(z + (size_t)m * 4096 + c0);
        fw[s][0] = b2f((uint16_t)(v.x & 0xffff)); fw[s][1] = b2f((uint16_t)(v.x >> 16));
        fw[s][2] = b2f((uint16_t)(v.y & 0xffff)); fw[s][3] = b2f((uint16_t)(v.y >> 16));
        fw[s][4] = b2f((uint16_t)(v.z & 0xffff)); fw[s][5] = b2f((uint16_t)(v.z >> 16));
        fw[s][6] = b2f((uint16_t)(v.w & 0xffff)); fw[s][7] = b2f((uint16_t)(v.w >> 16));
        uint16_t out[8];
#pragma unroll
        for (int c = 0; c < 8; ++c) {
            float a = bias[c];
#pragma unroll
            for (int j = 0; j < 4; ++j)         // tap j -> row m-3+j -> slot (t+1+j)&3
                a = fmaf(fw[(t + 1 + j) & 3][c], w[c][j], a);
            float sv = a / (1.f + __expf(-a));
            out[c] = f2b(sv);
        }
        uint4 o;
        o.x = (uint32_t)out[0] | ((uint32_t)out[1] << 16);
        o.y = (uint32_t)out[2] | ((uint32_t)out[3] << 16);
        o.z = (uint32_t)out[4] | ((uint32_t)out[5] << 16);
        o.w = (uint32_t)out[6] | ((uint32_t)out[7] << 16);
        *(uint4*)(u + (size_t)m * DINNER + c0) = o;
    }
}

// ---------------------------------------------------------------------------
// reduce split-K partials of x_proj: xdbl = sum_z xpart[z], dr16 = bf16(cols<64)
// grid: 8192 blocks x 128 threads (r = tid, guard r < 96)
// ---------------------------------------------------------------------------
__global__ __launch_bounds__(128) void reduce_xdbl_kernel(
    const float* __restrict__ xpart, float* __restrict__ xdbl,
    uint16_t* __restrict__ dr16)
{
    int m = blockIdx.x, r = threadIdx.x;
    if (r >= 96) return;
    const size_t stride = (size_t)MROWS * 96;
    size_t idx = (size_t)m * 96 + r;
    float s = xpart[idx] + xpart[stride + idx]
            + xpart[2 * stride + idx] + xpart[3 * stride + idx];
    xdbl[idx] = s;
    if (r < DTRANK) dr16[(size_t)m * DTRANK + r] = f2b(s);
}

// ---------------------------------------------------------------------------
// CHUNKED SELECTIVE SCAN, one thread = (b, d, chunk), 16 n-states in regs.
// ---------------------------------------------------------------------------
#define LOG2E 1.44269504088896340736f

__global__ __launch_bounds__(256) void scan_part1_kernel(
    const uint16_t* __restrict__ delta16, const uint16_t* __restrict__ u16,
    const float* __restrict__ xdbl, const float* __restrict__ A_log,
    float* __restrict__ Pws, float* __restrict__ Qws)
{
    int d = blockIdx.x * 256 + threadIdx.x;
    int b = blockIdx.y;
    int c = blockIdx.z;
    float ae[DSTATE];
#pragma unroll
    for (int n = 0; n < DSTATE; ++n)
        ae[n] = -__expf(A_log[d * DSTATE + n]) * LOG2E;
    float h[DSTATE], P[DSTATE];
#pragma unroll
    for (int n = 0; n < DSTATE; ++n) { h[n] = 0.f; P[n] = 1.f; }
    size_t mbase = (size_t)b * T_LEN + (size_t)c * CLEN;

#pragma unroll 2
    for (int t = 0; t < CLEN; ++t) {
        size_t m = mbase + t;
        float delta = b2f(delta16[m * DINNER + d]);
        float du    = delta * b2f(u16[m * DINNER + d]);
        float Bv[DSTATE];
        *(float4*)&Bv[0]  = *(const float4*)(xdbl + m * 96 + 64);
        *(float4*)&Bv[4]  = *(const float4*)(xdbl + m * 96 + 68);
        *(float4*)&Bv[8]  = *(const float4*)(xdbl + m * 96 + 72);
        *(float4*)&Bv[12] = *(const float4*)(xdbl + m * 96 + 76);
#pragma unroll
        for (int n = 0; n < DSTATE; ++n) {
            float w = __builtin_amdgcn_exp2f(delta * ae[n]);
            h[n] = fmaf(w, h[n], du * Bv[n]);
            P[n] *= w;
        }
    }
    float* Pp = Pws + (((size_t)c * BATCH + b) * DINNER + d) * DSTATE;
    float* Qp = Qws + (((size_t)c * BATCH + b) * DINNER + d) * DSTATE;
#pragma unroll
    for (int n = 0; n < DSTATE; n += 4) {
        *(float4*)(Pp + n) = *(float4*)&P[n];
        *(float4*)(Qp + n) = *(float4*)&h[n];
    }
}

// in-place: H0 for chunk c overwrites Pws[c]
__global__ __launch_bounds__(256) void scan_combine_kernel(
    float* __restrict__ Pws, const float* __restrict__ Qws)
{
    size_t i = (size_t)blockIdx.x * 256 + threadIdx.x;  // BATCH*DINNER*DSTATE
    const size_t stride = (size_t)BATCH * DINNER * DSTATE;
    float h = 0.f;
#pragma unroll
    for (int c = 0; c < NCHUNK; ++c) {
        float P = Pws[c * stride + i];
        float Q = Qws[c * stride + i];
        Pws[c * stride + i] = h;        // chunk-c initial state
        h = fmaf(P, h, Q);
    }
}

__global__ __launch_bounds__(256) void scan_part3_kernel(
    const uint16_t* __restrict__ delta16, const uint16_t* __restrict__ u16,
    const float* __restrict__ xdbl, const uint16_t* __restrict__ z16,
    const float* __restrict__ A_log, const float* __restrict__ Dvec,
    const float* __restrict__ H0ws, uint16_t* __restrict__ y16)
{
    int d = blockIdx.x * 256 + threadIdx.x;
    int b = blockIdx.y;
    int c = blockIdx.z;
    float ae[DSTATE];
#pragma unroll
    for (int n = 0; n < DSTATE; ++n)
        ae[n] = -__expf(A_log[d * DSTATE + n]) * LOG2E;
    float Dd = Dvec[d];
    float h[DSTATE];
    const float* H0p = H0ws + (((size_t)c * BATCH + b) * DINNER + d) * DSTATE;
#pragma unroll
    for (int n = 0; n < DSTATE; n += 4)
        *(float4*)&h[n] = *(const float4*)(H0p + n);
    size_t mbase = (size_t)b * T_LEN + (size_t)c * CLEN;

#pragma unroll 2
    for (int t = 0; t < CLEN; ++t) {
        size_t m = mbase + t;
        float delta = b2f(delta16[m * DINNER + d]);
        float uu    = b2f(u16[m * DINNER + d]);
        float rg    = b2f(z16[m * 4096 + DINNER + d]);
        float du    = delta * uu;
        float Bv[DSTATE], Cv[DSTATE];
        *(float4*)&Bv[0]  = *(const float4*)(xdbl + m * 96 + 64);
        *(float4*)&Bv[4]  = *(const float4*)(xdbl + m * 96 + 68);
        *(float4*)&Bv[8]  = *(const float4*)(xdbl + m * 96 + 72);
        *(float4*)&Bv[12] = *(const float4*)(xdbl + m * 96 + 76);
        *(float4*)&Cv[0]  = *(const float4*)(xdbl + m * 96 + 80);
        *(float4*)&Cv[4]  = *(const float4*)(xdbl + m * 96 + 84);
        *(float4*)&Cv[8]  = *(const float4*)(xdbl + m * 96 + 88);
        *(float4*)&Cv[12] = *(const float4*)(xdbl + m * 96 + 92);
        float y = 0.f;
#pragma unroll
        for (int n = 0; n < DSTATE; ++n) {
            float w = __builtin_amdgcn_exp2f(delta * ae[n]);
            h[n] = fmaf(w, h[n], du * Bv[n]);
            y = fmaf(h[n], Cv[n], y);
        }
        y = fmaf(uu, Dd, y);
        float sig = 1.f / (1.f + __expf(-rg));
        y16[m * DINNER + d] = f2b(y * rg * sig);
    }
}

// ---------------------------------------------------------------------------
extern "C" void kernel_launch(void* const* d_in, const int* in_sizes, int n_in,
                              void* d_out, int out_size, void* d_ws, size_t ws_size,
                              hipStream_t stream)
{
    const float* x     = (const float*)d_in[0];
    const float* W_in  = (const float*)d_in[1];
    const float* cw    = (const float*)d_in[2];
    const float* cb    = (const float*)d_in[3];
    const float* W_x   = (const float*)d_in[4];
    const float* W_dt  = (const float*)d_in[5];
    const float* b_dt  = (const float*)d_in[6];
    const float* A_log = (const float*)d_in[7];
    const float* Dv    = (const float*)d_in[8];
    const float* W_out = (const float*)d_in[9];

    char* ws = (char*)d_ws;
    size_t off = 0;
    uint16_t* xb16    = (uint16_t*)(ws + off); off += (size_t)MROWS * DMODEL * 2;   // 16.8 MB
    uint16_t* WinT    = (uint16_t*)(ws + off); off += (size_t)4096 * 1024 * 2;      //  8.4 MB
    uint16_t* WoutT   = (uint16_t*)(ws + off); off += (size_t)1024 * 2048 * 2;      //  4.2 MB
    uint16_t* WxT     = (uint16_t*)(ws + off); off += (size_t)128 * 2048 * 2;       //  0.5 MB
    uint16_t* WdtT    = (uint16_t*)(ws + off); off += (size_t)2048 * 64 * 2;        //  0.26 MB
    uint16_t* z16     = (uint16_t*)(ws + off); off += (size_t)MROWS * 4096 * 2;     // 67 MB (u_raw | res)
    uint16_t* u16     = (uint16_t*)(ws + off); off += (size_t)MROWS * DINNER * 2;   // 33.5 MB
    float*    xdbl    = (float*)(ws + off);    off += (size_t)MROWS * 96 * 4;       //  3.1 MB
    uint16_t* dr16    = (uint16_t*)(ws + off); off += (size_t)MROWS * 64 * 2;       //  1.0 MB
    uint16_t* delta16 = (uint16_t*)(ws + off); off += (size_t)MROWS * DINNER * 2;   // 33.5 MB
    uint16_t* y16     = (uint16_t*)(ws + off); off += (size_t)MROWS * DINNER * 2;   // 33.5 MB

    // xb16 (16.8 MB) is dead after in_proj; it hosts, in sequence:
    //   1) xpart: split-K partials of x_proj, 4 * 8192*96*4B = 12.6 MB
    //   2) Pws+Qws: 2 * 16*4*2048*16*4B = 16.8 MB (H0 in-place in Pws)
    float* xpart = (float*)xb16;
    float* Pws   = (float*)xb16;
    float* Qws   = Pws + (size_t)NCHUNK * BATCH * DINNER * DSTATE;

    dim3 tb(32, 8);
    convert_x_kernel<<<MROWS, 256, 0, stream>>>(x, xb16);
    transpose_cvt_kernel<<<dim3(32, 128), tb, 0, stream>>>(W_in,  WinT,  1024, 4096, 4096);
    transpose_cvt_kernel<<<dim3(64, 32),  tb, 0, stream>>>(W_out, WoutT, 2048, 1024, 1024);
    transpose_cvt_kernel<<<dim3(64, 4),   tb, 0, stream>>>(W_x,   WxT,   2048, 96, 128);
    transpose_cvt_kernel<<<dim3(2, 64),   tb, 0, stream>>>(W_dt,  WdtT,  64, 2048, 2048);

    // z = X @ W_in   (8192 x 4096 x 1024)
    gemm_bt_kernel<EPI_BF16, false><<<dim3(64, 32), 256, 0, stream>>>(
        xb16, WinT, z16, nullptr, 4096, 1024, 4096, 0);
    // u = silu(causal depthwise conv(z_u) + cb)   [register sliding window]
    conv_silu_kernel<<<MROWS / CROWS, 256, 0, stream>>>(z16, cw, cb, u16);
    // x_dbl partials = u @ W_x   (8192 x 96 x 2048), split-K x4
    gemm_bt_kernel<EPI_F32G, true><<<dim3(64, 1, 4), 256, 0, stream>>>(
        u16, WxT, xpart, nullptr, 96, 2048, 96, 512);
    // reduce partials -> xdbl fp32 + dr16 bf16
    reduce_xdbl_kernel<<<MROWS, 128, 0, stream>>>(xpart, xdbl, dr16);
    // delta = softplus(delta_raw @ W_dt + b_dt)   (8192 x 2048 x 64)
    gemm_bt_kernel<EPI_SP, false><<<dim3(64, 16), 256, 0, stream>>>(
        dr16, WdtT, delta16, b_dt, 2048, 64, 2048, 0);

    // chunked selective scan, register-resident states
    scan_part1_kernel<<<dim3(DINNER / 256, BATCH, NCHUNK), 256, 0, stream>>>(
        delta16, u16, xdbl, A_log, Pws, Qws);
    scan_combine_kernel<<<BATCH * DINNER * DSTATE / 256, 256, 0, stream>>>(
        Pws, Qws);
    scan_part3_kernel<<<dim3(DINNER / 256, BATCH, NCHUNK), 256, 0, stream>>>(
        delta16, u16, xdbl, z16, A_log, Dv, Pws, y16);

    // out = y @ W_out   (8192 x 1024 x 2048), remapped to (t,b,c) fp32
    gemm_bt_kernel<EPI_REMAP, false><<<dim3(64, 8), 256, 0, stream>>>(
        y16, WoutT, d_out, nullptr, 1024, 2048, 1024, 0);
}